// Round 1
// 622.746 us; speedup vs baseline: 1.0578x; 1.0578x over previous
//
#include <hip/hip_runtime.h>
#include <math.h>

#define D 256
#define BLOCK 256
#define NWAVES 4
#define R 4              // rows per wave per chunk

typedef float f32x4 __attribute__((ext_vector_type(4)));

// Pass 1: segment bounds. starts[s] = lower_bound(batch, s), starts[B] = N.
// batch[] is sorted; each boundary i (batch[i-1] != batch[i]) writes the
// starts[] entries for every segment in the gap. Total work O(N + B).
__global__ void seg_bounds_kernel(const int* __restrict__ batch,
                                  int* __restrict__ starts, int N, int B)
{
    int i = blockIdx.x * blockDim.x + threadIdx.x;
    const int stride = gridDim.x * blockDim.x;
    for (; i < N; i += stride) {
        const int cur  = batch[i];
        const int prev = (i == 0) ? -1 : batch[i - 1];
        for (int s = prev + 1; s <= cur; ++s) starts[s] = i;
        if (i == N - 1)
            for (int s = cur + 1; s <= B; ++s) starts[s] = N;
    }
}

// Pass 2: one block per segment. Each wave processes R consecutive rows per
// iteration (64 lanes x float4 = full 1 KB row, coalesced). Unroll-by-2
// register double-buffer: compute on bufA waits only vmcnt(R) while bufB's
// prefetch stays in flight -> the wave never drains to zero bytes in flight
// (the old nx->cx copy forced vmcnt(0) every chunk). Bounds come precomputed
// from ws; no binary search, no batch[] reads in the hot kernel.
__global__ __launch_bounds__(BLOCK, 4) void niche_attn_kernel(
    const float* __restrict__ x,
    const float* __restrict__ w,
    const float* __restrict__ bptr,
    const int*   __restrict__ starts,
    float*       __restrict__ out)
{
    const int seg  = blockIdx.x;
    const int tid  = threadIdx.x;
    const int wave = tid >> 6;
    const int lane = tid & 63;

    __shared__ float s_m[NWAVES];
    __shared__ float s_l[NWAVES];
    __shared__ float s_acc[NWAVES][D];   // 4 KB

    const int row_start = starts[seg];       // uniform -> scalar loads
    const int row_end   = starts[seg + 1];

    float* outp = out + (size_t)seg * D;

    if (row_end <= row_start) {          // empty segment -> zeros (block-uniform)
        outp[tid] = 0.f;
        return;
    }

    const int   col  = lane << 2;        // this lane's 4 columns
    const f32x4 w4   = *(const f32x4*)(w + col);
    const float bias = *bptr;

    float m = -INFINITY;
    float l = 0.f;
    f32x4 acc = {0.f, 0.f, 0.f, 0.f};

    const int step = NWAVES * R;
    int row = row_start + wave * R;      // this wave's first chunk

    f32x4 bufA[R], bufB[R];

    // Clamped, branch-free chunk load (dup rows at the tail hit cache; x has
    // zero reuse so use nontemporal hint to keep L2 clean for starts/out).
    auto loadc = [&](f32x4* buf, int r0) {
#pragma unroll
        for (int i = 0; i < R; ++i) {
            int r = r0 + i; r = (r < row_end) ? r : (row_end - 1);
            buf[i] = __builtin_nontemporal_load(
                         (const f32x4*)(x + (size_t)r * D + col));
        }
    };

    // R independent dots + interleaved butterflies, then one branchless
    // online-softmax update per chunk. First iter: m=-inf -> alpha=0.
    auto compute = [&](const f32x4* buf, int r0) {
        float s[R];
#pragma unroll
        for (int i = 0; i < R; ++i)
            s[i] = buf[i].x * w4.x + buf[i].y * w4.y
                 + buf[i].z * w4.z + buf[i].w * w4.w;
#pragma unroll
        for (int off = 32; off > 0; off >>= 1) {
#pragma unroll
            for (int i = 0; i < R; ++i)
                s[i] += __shfl_xor(s[i], off, 64);
        }
#pragma unroll
        for (int i = 0; i < R; ++i)
            s[i] = (r0 + i < row_end) ? (s[i] + bias) : -INFINITY;

        const float cmax = fmaxf(fmaxf(s[0], s[1]), fmaxf(s[2], s[3]));
        const float newm = fmaxf(m, cmax);
        const float alpha = __expf(m - newm);
        float p[R];
#pragma unroll
        for (int i = 0; i < R; ++i)
            p[i] = __expf(s[i] - newm);

        l = l * alpha + ((p[0] + p[1]) + (p[2] + p[3]));
        acc.x *= alpha; acc.y *= alpha; acc.z *= alpha; acc.w *= alpha;
#pragma unroll
        for (int i = 0; i < R; ++i) {
            acc.x = fmaf(buf[i].x, p[i], acc.x);
            acc.y = fmaf(buf[i].y, p[i], acc.y);
            acc.z = fmaf(buf[i].z, p[i], acc.z);
            acc.w = fmaf(buf[i].w, p[i], acc.w);
        }
        m = newm;
    };

    if (row < row_end) loadc(bufA, row);
    while (row < row_end) {
        int nrow = row + step;
        loadc(bufB, nrow);           // prefetch next chunk (clamped dups ok)
        compute(bufA, row);
        row = nrow;
        if (row >= row_end) break;
        nrow = row + step;
        loadc(bufA, nrow);
        compute(bufB, row);
        row = nrow;
    }

    // Merge the 4 waves' online-softmax states.
    if (lane == 0) { s_m[wave] = m; s_l[wave] = l; }
    __syncthreads();

    const float M = fmaxf(fmaxf(s_m[0], s_m[1]), fmaxf(s_m[2], s_m[3]));
    float L = 0.f;
#pragma unroll
    for (int wv = 0; wv < NWAVES; ++wv)
        L += s_l[wv] * __expf(s_m[wv] - M);     // idle wave: 0 * exp(-inf) = 0

    const float scale = __expf(m - M);          // 0 for waves with no rows
    s_acc[wave][col + 0] = acc.x * scale;
    s_acc[wave][col + 1] = acc.y * scale;
    s_acc[wave][col + 2] = acc.z * scale;
    s_acc[wave][col + 3] = acc.w * scale;
    __syncthreads();

    const float invL = 1.f / L;
    const float v = (s_acc[0][tid] + s_acc[1][tid]) + (s_acc[2][tid] + s_acc[3][tid]);
    outp[tid] = v * invL;
}

extern "C" void kernel_launch(void* const* d_in, const int* in_sizes, int n_in,
                              void* d_out, int out_size, void* d_ws, size_t ws_size,
                              hipStream_t stream)
{
    const float* x     = (const float*)d_in[0];
    const float* w     = (const float*)d_in[1];
    const float* b     = (const float*)d_in[2];
    const int*   batch = (const int*)d_in[3];
    float*       out   = (float*)d_out;
    int*         starts = (int*)d_ws;    // (B+1) ints

    const int N = in_sizes[3];          // batch[] length
    const int B = out_size / D;         // num_segments (4096)

    seg_bounds_kernel<<<1024, BLOCK, 0, stream>>>(batch, starts, N, B);
    niche_attn_kernel<<<B, BLOCK, 0, stream>>>(x, w, b, starts, out);
}